// Round 3
// baseline (320.953 us; speedup 1.0000x reference)
//
#include <hip/hip_runtime.h>
#include <cstddef>

#define NBATCH 16384
#define NX 256
#define NY 128
#define NU 128
#define NQ 128

// ---- workspace layout (float offsets) ----
#define WS_A      0         // 256x256  A = I - E
#define WS_S1     65536     // 256x256  S1 = 2I - E = I + A
#define WS_A2     131072    // A^2
#define WS_A4     196608    // A^4
#define WS_A8     262144    // A^8
#define WS_P2     327680    // (I+A)(I+A^2)
#define WS_P4     393216    // ...(I+A^4)
#define WS_P8     458752    // ...(I+A^8) = E^-1 (err ~0.2^16)
#define WS_WDX    524288    // 256x512 = [Einv F | Einv B1 | Einv B2]
#define WS_BASE   655360    // NBATCH x 128
#define WS_W      2752512   // NBATCH x 128

// ---------------------------------------------------------------------------
// A = I - E ; S1 = 2I - E
__global__ __launch_bounds__(256) void k_prep(const float* __restrict__ E,
                                              float* __restrict__ A,
                                              float* __restrict__ S1) {
  int i = blockIdx.x * 256 + threadIdx.x;
  float e = E[i];
  int r = i >> 8, c = i & 255;
  float id = (r == c) ? 1.0f : 0.0f;
  A[i]  = id - e;
  S1[i] = 2.0f * id - e;
}

// ---------------------------------------------------------------------------
// C(256 x 256, ldc) = A(256x256) @ B(256x256, ldb)  [+ X (ld=ldc)]
__global__ __launch_bounds__(256) void k_smallmm(const float* __restrict__ A,
                                                 const float* __restrict__ B,
                                                 const float* __restrict__ X,
                                                 float* __restrict__ C,
                                                 int ldb, int ldc, int addX) {
  __shared__ float As[32][36];
  __shared__ float Bs[32][36];
  int tid = threadIdx.x;
  int tx = tid & 15, ty = tid >> 4;
  int r0 = blockIdx.x * 32, c0 = blockIdx.y * 32;
  int lr = tid >> 3, lc = (tid & 7) * 4;
  float acc00 = 0.f, acc01 = 0.f, acc10 = 0.f, acc11 = 0.f;
  for (int k0 = 0; k0 < 256; k0 += 32) {
    float4 a4 = *(const float4*)&A[(size_t)(r0 + lr) * 256 + k0 + lc];
    float4 b4 = *(const float4*)&B[(size_t)(k0 + lr) * ldb + c0 + lc];
    __syncthreads();
    As[lr][lc+0] = a4.x; As[lr][lc+1] = a4.y; As[lr][lc+2] = a4.z; As[lr][lc+3] = a4.w;
    Bs[lr][lc+0] = b4.x; Bs[lr][lc+1] = b4.y; Bs[lr][lc+2] = b4.z; Bs[lr][lc+3] = b4.w;
    __syncthreads();
#pragma unroll
    for (int kk = 0; kk < 32; ++kk) {
      float a0 = As[ty*2+0][kk], a1 = As[ty*2+1][kk];
      float b0 = Bs[kk][tx*2+0], b1 = Bs[kk][tx*2+1];
      acc00 += a0*b0; acc01 += a0*b1; acc10 += a1*b0; acc11 += a1*b1;
    }
  }
  int r = r0 + ty*2, c = c0 + tx*2;
  if (addX) {
    acc00 += X[(size_t)r*ldc + c];     acc01 += X[(size_t)r*ldc + c+1];
    acc10 += X[(size_t)(r+1)*ldc + c]; acc11 += X[(size_t)(r+1)*ldc + c+1];
  }
  C[(size_t)r*ldc + c]       = acc00; C[(size_t)r*ldc + c+1]     = acc01;
  C[(size_t)(r+1)*ldc + c]   = acc10; C[(size_t)(r+1)*ldc + c+1] = acc11;
}

// ---------------------------------------------------------------------------
// Wdx(256x512) = P8 @ [F | B1 | B2]   (one fused launch, grid (8,16))
__global__ __launch_bounds__(256) void k_wdx(const float* __restrict__ P,
                                             const float* __restrict__ F,
                                             const float* __restrict__ B1,
                                             const float* __restrict__ B2,
                                             float* __restrict__ Wdx) {
  __shared__ float As[32][36];
  __shared__ float Bs[32][36];
  int tid = threadIdx.x;
  int tx = tid & 15, ty = tid >> 4;
  int r0 = blockIdx.x * 32, c0 = blockIdx.y * 32;
  const float* B; int ldb, cb;
  if (c0 < 256)      { B = F;  ldb = 256; cb = c0; }
  else if (c0 < 384) { B = B1; ldb = 128; cb = c0 - 256; }
  else               { B = B2; ldb = 128; cb = c0 - 384; }
  int lr = tid >> 3, lc = (tid & 7) * 4;
  float acc00 = 0.f, acc01 = 0.f, acc10 = 0.f, acc11 = 0.f;
  for (int k0 = 0; k0 < 256; k0 += 32) {
    float4 a4 = *(const float4*)&P[(size_t)(r0 + lr) * 256 + k0 + lc];
    float4 b4 = *(const float4*)&B[(size_t)(k0 + lr) * ldb + cb + lc];
    __syncthreads();
    As[lr][lc+0] = a4.x; As[lr][lc+1] = a4.y; As[lr][lc+2] = a4.z; As[lr][lc+3] = a4.w;
    Bs[lr][lc+0] = b4.x; Bs[lr][lc+1] = b4.y; Bs[lr][lc+2] = b4.z; Bs[lr][lc+3] = b4.w;
    __syncthreads();
#pragma unroll
    for (int kk = 0; kk < 32; ++kk) {
      float a0 = As[ty*2+0][kk], a1 = As[ty*2+1][kk];
      float b0 = Bs[kk][tx*2+0], b1 = Bs[kk][tx*2+1];
      acc00 += a0*b0; acc01 += a0*b1; acc10 += a1*b0; acc11 += a1*b1;
    }
  }
  int r = r0 + ty*2, c = c0 + tx*2;
  Wdx[(size_t)r*512 + c]       = acc00; Wdx[(size_t)r*512 + c+1]     = acc01;
  Wdx[(size_t)(r+1)*512 + c]   = acc10; Wdx[(size_t)(r+1)*512 + c+1] = acc11;
}

// ---------------------------------------------------------------------------
// base = x @ C1^T + u @ D12^T + bv      (NBATCH x 128)
// BM=64, BN=64, BK=16, 256 threads, 4x4 per thread. grid (256, 2)
__global__ __launch_bounds__(256) void k_base(const float* __restrict__ x,
                                              const float* __restrict__ u,
                                              const float* __restrict__ C1,
                                              const float* __restrict__ D12,
                                              const float* __restrict__ bv,
                                              float* __restrict__ baseo) {
  __shared__ float As[16][68];
  __shared__ float Bs[16][68];
  int tid = threadIdx.x;
  int tx = tid & 15, ty = tid >> 4;
  int row0 = blockIdx.x * 64, n0 = blockIdx.y * 64;
  int lm = tid >> 2, lq = (tid & 3) * 4;
  float acc[4][4] = {};
  for (int k0 = 0; k0 < 384; k0 += 16) {
    const float* ap;
    if (k0 < 256) ap = x + (size_t)(row0 + lm) * 256 + k0 + lq;
    else          ap = u + (size_t)(row0 + lm) * 128 + (k0 - 256) + lq;
    const float* bp;
    int nrow = n0 + lm;
    if (k0 < 256) bp = C1  + (size_t)nrow * 256 + k0 + lq;
    else          bp = D12 + (size_t)nrow * 128 + (k0 - 256) + lq;
    float4 a4 = *(const float4*)ap;
    float4 b4 = *(const float4*)bp;
    __syncthreads();
    As[lq+0][lm] = a4.x; As[lq+1][lm] = a4.y; As[lq+2][lm] = a4.z; As[lq+3][lm] = a4.w;
    Bs[lq+0][lm] = b4.x; Bs[lq+1][lm] = b4.y; Bs[lq+2][lm] = b4.z; Bs[lq+3][lm] = b4.w;
    __syncthreads();
#pragma unroll
    for (int kk = 0; kk < 16; ++kk) {
      float4 av = *(const float4*)&As[kk][ty*4];
      float4 bvv = *(const float4*)&Bs[kk][tx*4];
      float a[4] = {av.x, av.y, av.z, av.w};
      float b[4] = {bvv.x, bvv.y, bvv.z, bvv.w};
#pragma unroll
      for (int i = 0; i < 4; ++i)
#pragma unroll
        for (int j = 0; j < 4; ++j)
          acc[i][j] += a[i] * b[j];
    }
  }
#pragma unroll
  for (int i = 0; i < 4; ++i) {
    int r = row0 + ty*4 + i;
#pragma unroll
    for (int j = 0; j < 4; ++j) {
      int c = n0 + tx*4 + j;
      baseo[(size_t)r*128 + c] = acc[i][j] + bv[c];
    }
  }
}

// ---------------------------------------------------------------------------
// Sequential tanh solve, rank-1 update form. Lane l holds s[k'] for k'=l, l+64.
// D11^T staged in LDS with XOR swizzle (conflict-free transpose write + read).
__global__ __launch_bounds__(256) void k_wsolve(const float* __restrict__ baseo,
                                               const float* __restrict__ D11,
                                               const float* __restrict__ Lam,
                                               float* __restrict__ wout) {
  __shared__ float d11t[128 * 128];   // d11t[k*128 + (j ^ (k&31))] = D11[j][k]
  int tid = threadIdx.x;
  for (int idx = tid; idx < 128 * 128; idx += 256) {
    int r = idx >> 7;     // D11 row j  (coalesced global read)
    int c = idx & 127;    // D11 col k
    d11t[c * 128 + (r ^ (c & 31))] = D11[idx];
  }
  int lane = tid & 63, wave = tid >> 6;
  // per-lane 2/lambda, broadcast later via shfl
  float rl2a = 2.0f / Lam[lane];
  float rl2b = 2.0f / Lam[64 + lane];
  __syncthreads();
  size_t rowbase = (size_t)blockIdx.x * 32 + (size_t)wave * 8;
  float s0[8], s1[8], w0[8], w1[8];
#pragma unroll
  for (int r = 0; r < 8; ++r) {
    s0[r] = baseo[(rowbase + r) * 128 + lane];
    s1[r] = baseo[(rowbase + r) * 128 + 64 + lane];
    w0[r] = 0.f; w1[r] = 0.f;
  }
  for (int k = 0; k < 64; ++k) {
    float d0 = d11t[k * 128 + (lane ^ (k & 31))];
    float d1 = d11t[k * 128 + ((64 + lane) ^ (k & 31))];
    float rl2 = __shfl(rl2a, k, 64);
#pragma unroll
    for (int r = 0; r < 8; ++r) {
      float sk = __shfl(s0[r], k, 64);
      float e = __expf(sk * rl2);                       // exp(2v)
      float wk = 1.0f - 2.0f * __builtin_amdgcn_rcpf(e + 1.0f);  // tanh(v)
      s0[r] += wk * d0;
      s1[r] += wk * d1;
      if (lane == k) w0[r] = wk;
    }
  }
  for (int k = 64; k < 128; ++k) {
    float d0 = d11t[k * 128 + (lane ^ (k & 31))];
    float d1 = d11t[k * 128 + ((64 + lane) ^ (k & 31))];
    float rl2 = __shfl(rl2b, k - 64, 64);
#pragma unroll
    for (int r = 0; r < 8; ++r) {
      float sk = __shfl(s1[r], k - 64, 64);
      float e = __expf(sk * rl2);
      float wk = 1.0f - 2.0f * __builtin_amdgcn_rcpf(e + 1.0f);
      s0[r] += wk * d0;
      s1[r] += wk * d1;
      if (lane == (k - 64)) w1[r] = wk;
    }
  }
#pragma unroll
  for (int r = 0; r < 8; ++r) {
    wout[(rowbase + r) * 128 + lane]      = w0[r];
    wout[(rowbase + r) * 128 + 64 + lane] = w1[r];
  }
}

// ---------------------------------------------------------------------------
// out = [x | w | u] @ Wcat^T ; rows 0..255 of Wcat = Wdx (ws), 256..383 = [C2|D21|D22]
// BM=128, BN=64, BK=16, 256 threads, 8x4 per thread. grid (128, 6)
__global__ __launch_bounds__(256) void k_final(const float* __restrict__ x,
                                               const float* __restrict__ u,
                                               const float* __restrict__ w,
                                               const float* __restrict__ Wdx,
                                               const float* __restrict__ C2,
                                               const float* __restrict__ D21,
                                               const float* __restrict__ D22,
                                               float* __restrict__ out) {
  __shared__ float As[16][132];
  __shared__ float Bs[16][68];
  int tid = threadIdx.x;
  int tx = tid & 15, ty = tid >> 4;
  int row0 = blockIdx.x * 128, n0 = blockIdx.y * 64;
  float acc[8][4] = {};
  int ln = tid >> 2, lqb = (tid & 3) * 4;
  for (int k0 = 0; k0 < 512; k0 += 16) {
    // ---- A tile: 128x16, 2 float4 per thread ----
    float4 av[2];
#pragma unroll
    for (int i = 0; i < 2; ++i) {
      int t = tid + i * 256;
      int lm = t >> 2, lq = (t & 3) * 4;
      int row = row0 + lm;
      const float* ap;
      if (k0 < 256)      ap = x + (size_t)row * 256 + k0 + lq;
      else if (k0 < 384) ap = w + (size_t)row * 128 + (k0 - 256) + lq;
      else               ap = u + (size_t)row * 128 + (k0 - 384) + lq;
      av[i] = *(const float4*)ap;
    }
    // ---- B tile: 64x16, 1 float4 per thread ----
    int nrow = n0 + ln;
    const float* bp;
    if (n0 < 256) bp = Wdx + (size_t)nrow * 512 + k0 + lqb;
    else {
      int nn = nrow - 256;
      if (k0 < 256)      bp = C2  + (size_t)nn * 256 + k0 + lqb;
      else if (k0 < 384) bp = D21 + (size_t)nn * 128 + (k0 - 256) + lqb;
      else               bp = D22 + (size_t)nn * 128 + (k0 - 384) + lqb;
    }
    float4 b4 = *(const float4*)bp;
    __syncthreads();
#pragma unroll
    for (int i = 0; i < 2; ++i) {
      int t = tid + i * 256;
      int lm = t >> 2, lq = (t & 3) * 4;
      As[lq+0][lm] = av[i].x; As[lq+1][lm] = av[i].y;
      As[lq+2][lm] = av[i].z; As[lq+3][lm] = av[i].w;
    }
    Bs[lqb+0][ln] = b4.x; Bs[lqb+1][ln] = b4.y; Bs[lqb+2][ln] = b4.z; Bs[lqb+3][ln] = b4.w;
    __syncthreads();
#pragma unroll
    for (int kk = 0; kk < 16; ++kk) {
      float4 a0 = *(const float4*)&As[kk][ty*8];
      float4 a1 = *(const float4*)&As[kk][ty*8 + 4];
      float4 bb = *(const float4*)&Bs[kk][tx*4];
      float a[8] = {a0.x, a0.y, a0.z, a0.w, a1.x, a1.y, a1.z, a1.w};
      float b[4] = {bb.x, bb.y, bb.z, bb.w};
#pragma unroll
      for (int i = 0; i < 8; ++i)
#pragma unroll
        for (int j = 0; j < 4; ++j)
          acc[i][j] += a[i] * b[j];
    }
  }
  // epilogue: n<256 -> dx, else -> y
#pragma unroll
  for (int i = 0; i < 8; ++i) {
    int r = row0 + ty*8 + i;
#pragma unroll
    for (int j = 0; j < 4; ++j) {
      int n = n0 + tx*4 + j;
      if (n0 < 256) out[(size_t)r * 256 + n] = acc[i][j];
      else          out[(size_t)NBATCH * 256 + (size_t)r * 128 + (n - 256)] = acc[i][j];
    }
  }
}

// ---------------------------------------------------------------------------
extern "C" void kernel_launch(void* const* d_in, const int* in_sizes, int n_in,
                              void* d_out, int out_size, void* d_ws, size_t ws_size,
                              hipStream_t stream) {
  (void)in_sizes; (void)n_in; (void)out_size; (void)ws_size;
  const float* x   = (const float*)d_in[0];
  const float* u   = (const float*)d_in[1];
  const float* F   = (const float*)d_in[2];
  const float* B1  = (const float*)d_in[3];
  const float* B2  = (const float*)d_in[4];
  const float* C1  = (const float*)d_in[5];
  const float* C2  = (const float*)d_in[6];
  const float* D11 = (const float*)d_in[7];
  const float* D12 = (const float*)d_in[8];
  const float* D21 = (const float*)d_in[9];
  const float* D22 = (const float*)d_in[10];
  const float* E   = (const float*)d_in[11];
  const float* Lam = (const float*)d_in[12];
  const float* bv  = (const float*)d_in[13];
  float* out = (float*)d_out;
  float* ws  = (float*)d_ws;

  float* A    = ws + WS_A;
  float* S1   = ws + WS_S1;
  float* A2   = ws + WS_A2;
  float* A4   = ws + WS_A4;
  float* A8   = ws + WS_A8;
  float* P2   = ws + WS_P2;
  float* P4   = ws + WS_P4;
  float* P8   = ws + WS_P8;
  float* Wdx  = ws + WS_WDX;
  float* base = ws + WS_BASE;
  float* wbuf = ws + WS_W;

  // E^-1 via Neumann product: (I+A)(I+A^2)(I+A^4)(I+A^8), A = I-E, ||A||~0.2
  k_prep<<<256, 256, 0, stream>>>(E, A, S1);
  k_smallmm<<<dim3(8, 8), 256, 0, stream>>>(A,  A,  nullptr, A2, 256, 256, 0);  // A2 = A@A
  k_smallmm<<<dim3(8, 8), 256, 0, stream>>>(A2, A2, nullptr, A4, 256, 256, 0);  // A4
  k_smallmm<<<dim3(8, 8), 256, 0, stream>>>(A4, A4, nullptr, A8, 256, 256, 0);  // A8
  k_smallmm<<<dim3(8, 8), 256, 0, stream>>>(S1, A2, S1,      P2, 256, 256, 1);  // P2 = S1 + S1@A2
  k_smallmm<<<dim3(8, 8), 256, 0, stream>>>(P2, A4, P2,      P4, 256, 256, 1);  // P4 = P2 + P2@A4
  k_smallmm<<<dim3(8, 8), 256, 0, stream>>>(P4, A8, P4,      P8, 256, 256, 1);  // P8 = E^-1
  k_wdx<<<dim3(8, 16), 256, 0, stream>>>(P8, F, B1, B2, Wdx);                   // [EinvF|EinvB1|EinvB2]

  k_base<<<dim3(256, 2), 256, 0, stream>>>(x, u, C1, D12, bv, base);
  k_wsolve<<<512, 256, 0, stream>>>(base, D11, Lam, wbuf);
  k_final<<<dim3(128, 6), 256, 0, stream>>>(x, u, wbuf, Wdx, C2, D21, D22, out);
}

// Round 4
// 275.442 us; speedup vs baseline: 1.1652x; 1.1652x over previous
//
#include <hip/hip_runtime.h>
#include <hip/hip_bf16.h>
#include <cstddef>

#define NBATCH 16384
#define NX 256
#define NY 128
#define NU 128
#define NQ 128

// ---- workspace layout (float offsets) ----
#define WS_A      0         // 256x256  A = I - E
#define WS_S1     65536     // 256x256  S1 = 2I - E = I + A
#define WS_A2     131072    // A^2
#define WS_A4     196608    // A^4
#define WS_A8     262144    // A^8
#define WS_P2     327680    // (I+A)(I+A^2)
#define WS_P4     393216    // ...(I+A^4)
#define WS_P8     458752    // ...(I+A^8) = E^-1 (err ~0.2^16)
#define WS_WDX    524288    // 256x512 = [Einv F | Einv B1 | Einv B2]
#define WS_BASE   655360    // NBATCH x 128
#define WS_W      2752512   // NBATCH x 128 (fp32 w)
#define WS_WCH    4849664   // Wcat hi: 384x512 bf16 (98304 floats)
#define WS_WCL    4947968   // Wcat lo
#define WS_WBH    5046272   // Wbase hi: 128x384 bf16 (24576 floats)
#define WS_WBL    5070848   // Wbase lo
// end: 5095424 floats = 20.4 MB

typedef __attribute__((ext_vector_type(8))) short bf8_t;   // 8 bf16 (4 VGPR)
typedef __attribute__((ext_vector_type(4))) float f4_t;    // MFMA acc

// ---------------------------------------------------------------------------
// A = I - E ; S1 = 2I - E
__global__ __launch_bounds__(256) void k_prep(const float* __restrict__ E,
                                              float* __restrict__ A,
                                              float* __restrict__ S1) {
  int i = blockIdx.x * 256 + threadIdx.x;
  float e = E[i];
  int r = i >> 8, c = i & 255;
  float id = (r == c) ? 1.0f : 0.0f;
  A[i]  = id - e;
  S1[i] = 2.0f * id - e;
}

// ---------------------------------------------------------------------------
// C(256 x 256) = A(256x256) @ B(256x256, ldb)  [+ X]
__global__ __launch_bounds__(256) void k_smallmm(const float* __restrict__ A,
                                                 const float* __restrict__ B,
                                                 const float* __restrict__ X,
                                                 float* __restrict__ C,
                                                 int ldb, int ldc, int addX) {
  __shared__ float As[32][36];
  __shared__ float Bs[32][36];
  int tid = threadIdx.x;
  int tx = tid & 15, ty = tid >> 4;
  int r0 = blockIdx.x * 32, c0 = blockIdx.y * 32;
  int lr = tid >> 3, lc = (tid & 7) * 4;
  float acc00 = 0.f, acc01 = 0.f, acc10 = 0.f, acc11 = 0.f;
  for (int k0 = 0; k0 < 256; k0 += 32) {
    float4 a4 = *(const float4*)&A[(size_t)(r0 + lr) * 256 + k0 + lc];
    float4 b4 = *(const float4*)&B[(size_t)(k0 + lr) * ldb + c0 + lc];
    __syncthreads();
    As[lr][lc+0] = a4.x; As[lr][lc+1] = a4.y; As[lr][lc+2] = a4.z; As[lr][lc+3] = a4.w;
    Bs[lr][lc+0] = b4.x; Bs[lr][lc+1] = b4.y; Bs[lr][lc+2] = b4.z; Bs[lr][lc+3] = b4.w;
    __syncthreads();
#pragma unroll
    for (int kk = 0; kk < 32; ++kk) {
      float a0 = As[ty*2+0][kk], a1 = As[ty*2+1][kk];
      float b0 = Bs[kk][tx*2+0], b1 = Bs[kk][tx*2+1];
      acc00 += a0*b0; acc01 += a0*b1; acc10 += a1*b0; acc11 += a1*b1;
    }
  }
  int r = r0 + ty*2, c = c0 + tx*2;
  if (addX) {
    acc00 += X[(size_t)r*ldc + c];     acc01 += X[(size_t)r*ldc + c+1];
    acc10 += X[(size_t)(r+1)*ldc + c]; acc11 += X[(size_t)(r+1)*ldc + c+1];
  }
  C[(size_t)r*ldc + c]       = acc00; C[(size_t)r*ldc + c+1]     = acc01;
  C[(size_t)(r+1)*ldc + c]   = acc10; C[(size_t)(r+1)*ldc + c+1] = acc11;
}

// ---------------------------------------------------------------------------
// Wdx(256x512) = P8 @ [F | B1 | B2]
__global__ __launch_bounds__(256) void k_wdx(const float* __restrict__ P,
                                             const float* __restrict__ F,
                                             const float* __restrict__ B1,
                                             const float* __restrict__ B2,
                                             float* __restrict__ Wdx) {
  __shared__ float As[32][36];
  __shared__ float Bs[32][36];
  int tid = threadIdx.x;
  int tx = tid & 15, ty = tid >> 4;
  int r0 = blockIdx.x * 32, c0 = blockIdx.y * 32;
  const float* B; int ldb, cb;
  if (c0 < 256)      { B = F;  ldb = 256; cb = c0; }
  else if (c0 < 384) { B = B1; ldb = 128; cb = c0 - 256; }
  else               { B = B2; ldb = 128; cb = c0 - 384; }
  int lr = tid >> 3, lc = (tid & 7) * 4;
  float acc00 = 0.f, acc01 = 0.f, acc10 = 0.f, acc11 = 0.f;
  for (int k0 = 0; k0 < 256; k0 += 32) {
    float4 a4 = *(const float4*)&P[(size_t)(r0 + lr) * 256 + k0 + lc];
    float4 b4 = *(const float4*)&B[(size_t)(k0 + lr) * ldb + cb + lc];
    __syncthreads();
    As[lr][lc+0] = a4.x; As[lr][lc+1] = a4.y; As[lr][lc+2] = a4.z; As[lr][lc+3] = a4.w;
    Bs[lr][lc+0] = b4.x; Bs[lr][lc+1] = b4.y; Bs[lr][lc+2] = b4.z; Bs[lr][lc+3] = b4.w;
    __syncthreads();
#pragma unroll
    for (int kk = 0; kk < 32; ++kk) {
      float a0 = As[ty*2+0][kk], a1 = As[ty*2+1][kk];
      float b0 = Bs[kk][tx*2+0], b1 = Bs[kk][tx*2+1];
      acc00 += a0*b0; acc01 += a0*b1; acc10 += a1*b0; acc11 += a1*b1;
    }
  }
  int r = r0 + ty*2, c = c0 + tx*2;
  Wdx[(size_t)r*512 + c]       = acc00; Wdx[(size_t)r*512 + c+1]     = acc01;
  Wdx[(size_t)(r+1)*512 + c]   = acc10; Wdx[(size_t)(r+1)*512 + c+1] = acc11;
}

// ---------------------------------------------------------------------------
// split fp32 -> bf16 hi/lo (rounding mode irrelevant: lo catches remainder)
__device__ inline void splitbf(float a, unsigned short& h, unsigned short& l) {
  __hip_bfloat16 hb = __float2bfloat16(a);
  float hf = __bfloat162float(hb);
  __hip_bfloat16 lb = __float2bfloat16(a - hf);
  h = __builtin_bit_cast(unsigned short, hb);
  l = __builtin_bit_cast(unsigned short, lb);
}

// Preconvert weights: Wcat(384x512) = [Wdx ; C2|D21|D22], Wbase(128x384) = [C1|D12]
__global__ __launch_bounds__(256) void k_wprep(const float* __restrict__ Wdx,
                                               const float* __restrict__ C2,
                                               const float* __restrict__ D21,
                                               const float* __restrict__ D22,
                                               const float* __restrict__ C1,
                                               const float* __restrict__ D12,
                                               ushort* __restrict__ Wh,
                                               ushort* __restrict__ Wl,
                                               ushort* __restrict__ Wbh,
                                               ushort* __restrict__ Wbl) {
  int i = blockIdx.x * 256 + threadIdx.x;
  if (i < 384 * 512) {
    int n = i >> 9, k = i & 511;
    float v;
    if (n < 256) v = Wdx[(size_t)n * 512 + k];
    else {
      int nn = n - 256;
      if (k < 256)      v = C2[(size_t)nn * 256 + k];
      else if (k < 384) v = D21[(size_t)nn * 128 + (k - 256)];
      else              v = D22[(size_t)nn * 128 + (k - 384)];
    }
    unsigned short h, l; splitbf(v, h, l);
    Wh[i] = h; Wl[i] = l;
  } else {
    int j = i - 384 * 512;     // < 128*384
    int n = j / 384, k = j - n * 384;
    float v = (k < 256) ? C1[(size_t)n * 256 + k] : D12[(size_t)n * 128 + (k - 256)];
    unsigned short h, l; splitbf(v, h, l);
    Wbh[j] = h; Wbl[j] = l;
  }
}

// ---------------------------------------------------------------------------
// Split-bf16 MFMA GEMM: C[m][n] = sum_k A[m][k]*W[n][k] (+bias)
// BM=128, BN=64, BK=32, 256 thr (4 waves 2x2), per wave 64x32 out.
// A staged in LDS: row = [hi 32bf16 | lo 32bf16] = 128B = 8 chunks, chunk ^= row&7.
// B fragments read directly from preconverted bf16 global (L2-resident).
// k_base: K=384, A=[x|u], W=Wbase, out=base(+bv). k_final: K=512, A=[x|w|u],
// W=Wcat, out: n<256 -> dx, else y.
template <int KTOT, bool FINAL>
__global__ __launch_bounds__(256) void k_gemm_split(const float* __restrict__ x,
                                                    const float* __restrict__ u,
                                                    const float* __restrict__ w,
                                                    const ushort* __restrict__ Wh,
                                                    const ushort* __restrict__ Wl,
                                                    const float* __restrict__ bv,
                                                    float* __restrict__ out) {
  __shared__ __align__(16) ushort sA[128 * 64];   // 16 KB
  const int tid  = threadIdx.x;
  const int lane = tid & 63, wav = tid >> 6;
  const int wm = wav >> 1, wn = wav & 1;
  const int row0 = blockIdx.x * 128;
  const int n0   = blockIdx.y * 64;

  const int srow = wav * 32 + (lane & 31);   // staged row 0..127
  const int h    = lane >> 5;                // k-half 0/1
  const size_t gr = (size_t)(row0 + srow);

  const int fr = lane & 15;                  // fragment row/col
  const int fc = lane >> 4;                  // fragment k-chunk 0..3

  f4_t acc[4][2];
#pragma unroll
  for (int i = 0; i < 4; ++i)
#pragma unroll
    for (int j = 0; j < 2; ++j) acc[i][j] = f4_t{0.f, 0.f, 0.f, 0.f};

  for (int k0 = 0; k0 < KTOT; k0 += 32) {
    // ---- load 16 fp32 of A (one row-segment) + split ----
    int kseg = k0 + h * 16;
    const float* ap;
    if (FINAL) {
      if (kseg < 256)      ap = x + gr * 256 + kseg;
      else if (kseg < 384) ap = w + gr * 128 + (kseg - 256);
      else                 ap = u + gr * 128 + (kseg - 384);
    } else {
      if (kseg < 256)      ap = x + gr * 256 + kseg;
      else                 ap = u + gr * 128 + (kseg - 256);
    }
    float fv[16];
#pragma unroll
    for (int q = 0; q < 4; ++q) {
      float4 f = *(const float4*)(ap + q * 4);
      fv[q*4+0] = f.x; fv[q*4+1] = f.y; fv[q*4+2] = f.z; fv[q*4+3] = f.w;
    }
    unsigned short hb[16], lb[16];
#pragma unroll
    for (int e = 0; e < 16; ++e) splitbf(fv[e], hb[e], lb[e]);

    // ---- B fragments straight from global (L2-hot) ----
    uint4 bhr[2], blr[2];
#pragma unroll
    for (int ns = 0; ns < 2; ++ns) {
      int n = n0 + wn * 32 + ns * 16 + fr;
      size_t boff = (size_t)n * KTOT + k0 + fc * 8;
      bhr[ns] = *(const uint4*)&Wh[boff];
      blr[ns] = *(const uint4*)&Wl[boff];
    }

    __syncthreads();
    // ---- stage A hi/lo into swizzled LDS ----
    {
      const int cid0 = 2 * h, cid1 = 2 * h + 1;
      uint4 v;
      v.x = hb[0] | ((unsigned)hb[1] << 16); v.y = hb[2]  | ((unsigned)hb[3] << 16);
      v.z = hb[4] | ((unsigned)hb[5] << 16); v.w = hb[6]  | ((unsigned)hb[7] << 16);
      *(uint4*)&sA[srow * 64 + ((cid0 ^ (srow & 7)) << 3)] = v;
      v.x = hb[8] | ((unsigned)hb[9] << 16); v.y = hb[10] | ((unsigned)hb[11] << 16);
      v.z = hb[12]| ((unsigned)hb[13]<< 16); v.w = hb[14] | ((unsigned)hb[15] << 16);
      *(uint4*)&sA[srow * 64 + ((cid1 ^ (srow & 7)) << 3)] = v;
      v.x = lb[0] | ((unsigned)lb[1] << 16); v.y = lb[2]  | ((unsigned)lb[3] << 16);
      v.z = lb[4] | ((unsigned)lb[5] << 16); v.w = lb[6]  | ((unsigned)lb[7] << 16);
      *(uint4*)&sA[srow * 64 + (((4 + cid0) ^ (srow & 7)) << 3)] = v;
      v.x = lb[8] | ((unsigned)lb[9] << 16); v.y = lb[10] | ((unsigned)lb[11] << 16);
      v.z = lb[12]| ((unsigned)lb[13]<< 16); v.w = lb[14] | ((unsigned)lb[15] << 16);
      *(uint4*)&sA[srow * 64 + (((5 + cid0) ^ (srow & 7)) << 3)] = v;
    }
    __syncthreads();

    // ---- fragments + MFMA (3-product split) ----
    bf8_t ah[4], al[4];
#pragma unroll
    for (int ms = 0; ms < 4; ++ms) {
      int r = wm * 64 + ms * 16 + fr;
      ah[ms] = *(const bf8_t*)&sA[r * 64 + (((fc    ) ^ (r & 7)) << 3)];
      al[ms] = *(const bf8_t*)&sA[r * 64 + (((fc + 4) ^ (r & 7)) << 3)];
    }
#pragma unroll
    for (int ns = 0; ns < 2; ++ns) {
      bf8_t bh = __builtin_bit_cast(bf8_t, bhr[ns]);
      bf8_t bl = __builtin_bit_cast(bf8_t, blr[ns]);
#pragma unroll
      for (int ms = 0; ms < 4; ++ms) {
        acc[ms][ns] = __builtin_amdgcn_mfma_f32_16x16x32_bf16(ah[ms], bh, acc[ms][ns], 0, 0, 0);
        acc[ms][ns] = __builtin_amdgcn_mfma_f32_16x16x32_bf16(ah[ms], bl, acc[ms][ns], 0, 0, 0);
        acc[ms][ns] = __builtin_amdgcn_mfma_f32_16x16x32_bf16(al[ms], bh, acc[ms][ns], 0, 0, 0);
      }
    }
  }

  // ---- epilogue: C/D layout col=lane&15, row=(lane>>4)*4+j ----
#pragma unroll
  for (int ms = 0; ms < 4; ++ms) {
#pragma unroll
    for (int ns = 0; ns < 2; ++ns) {
#pragma unroll
      for (int j = 0; j < 4; ++j) {
        int m = row0 + wm * 64 + ms * 16 + fc * 4 + j;
        int n = n0 + wn * 32 + ns * 16 + fr;
        float v = acc[ms][ns][j];
        if (FINAL) {
          if (n0 < 256) out[(size_t)m * 256 + n] = v;
          else          out[(size_t)NBATCH * 256 + (size_t)m * 128 + (n - 256)] = v;
        } else {
          out[(size_t)m * 128 + n] = v + bv[n];
        }
      }
    }
  }
}

// ---------------------------------------------------------------------------
// Sequential tanh solve, rank-1 update form (unchanged).
__global__ __launch_bounds__(256) void k_wsolve(const float* __restrict__ baseo,
                                               const float* __restrict__ D11,
                                               const float* __restrict__ Lam,
                                               float* __restrict__ wout) {
  __shared__ float d11t[128 * 128];
  int tid = threadIdx.x;
  for (int idx = tid; idx < 128 * 128; idx += 256) {
    int r = idx >> 7;
    int c = idx & 127;
    d11t[c * 128 + (r ^ (c & 31))] = D11[idx];
  }
  int lane = tid & 63, wave = tid >> 6;
  float rl2a = 2.0f / Lam[lane];
  float rl2b = 2.0f / Lam[64 + lane];
  __syncthreads();
  size_t rowbase = (size_t)blockIdx.x * 32 + (size_t)wave * 8;
  float s0[8], s1[8], w0[8], w1[8];
#pragma unroll
  for (int r = 0; r < 8; ++r) {
    s0[r] = baseo[(rowbase + r) * 128 + lane];
    s1[r] = baseo[(rowbase + r) * 128 + 64 + lane];
    w0[r] = 0.f; w1[r] = 0.f;
  }
  for (int k = 0; k < 64; ++k) {
    float d0 = d11t[k * 128 + (lane ^ (k & 31))];
    float d1 = d11t[k * 128 + ((64 + lane) ^ (k & 31))];
    float rl2 = __shfl(rl2a, k, 64);
#pragma unroll
    for (int r = 0; r < 8; ++r) {
      float sk = __shfl(s0[r], k, 64);
      float e = __expf(sk * rl2);
      float wk = 1.0f - 2.0f * __builtin_amdgcn_rcpf(e + 1.0f);
      s0[r] += wk * d0;
      s1[r] += wk * d1;
      if (lane == k) w0[r] = wk;
    }
  }
  for (int k = 64; k < 128; ++k) {
    float d0 = d11t[k * 128 + (lane ^ (k & 31))];
    float d1 = d11t[k * 128 + ((64 + lane) ^ (k & 31))];
    float rl2 = __shfl(rl2b, k - 64, 64);
#pragma unroll
    for (int r = 0; r < 8; ++r) {
      float sk = __shfl(s1[r], k - 64, 64);
      float e = __expf(sk * rl2);
      float wk = 1.0f - 2.0f * __builtin_amdgcn_rcpf(e + 1.0f);
      s0[r] += wk * d0;
      s1[r] += wk * d1;
      if (lane == (k - 64)) w1[r] = wk;
    }
  }
#pragma unroll
  for (int r = 0; r < 8; ++r) {
    wout[(rowbase + r) * 128 + lane]      = w0[r];
    wout[(rowbase + r) * 128 + 64 + lane] = w1[r];
  }
}

// ---------------------------------------------------------------------------
extern "C" void kernel_launch(void* const* d_in, const int* in_sizes, int n_in,
                              void* d_out, int out_size, void* d_ws, size_t ws_size,
                              hipStream_t stream) {
  (void)in_sizes; (void)n_in; (void)out_size; (void)ws_size;
  const float* x   = (const float*)d_in[0];
  const float* u   = (const float*)d_in[1];
  const float* F   = (const float*)d_in[2];
  const float* B1  = (const float*)d_in[3];
  const float* B2  = (const float*)d_in[4];
  const float* C1  = (const float*)d_in[5];
  const float* C2  = (const float*)d_in[6];
  const float* D11 = (const float*)d_in[7];
  const float* D12 = (const float*)d_in[8];
  const float* D21 = (const float*)d_in[9];
  const float* D22 = (const float*)d_in[10];
  const float* E   = (const float*)d_in[11];
  const float* Lam = (const float*)d_in[12];
  const float* bv  = (const float*)d_in[13];
  float* out = (float*)d_out;
  float* ws  = (float*)d_ws;

  float* A    = ws + WS_A;
  float* S1   = ws + WS_S1;
  float* A2   = ws + WS_A2;
  float* A4   = ws + WS_A4;
  float* A8   = ws + WS_A8;
  float* P2   = ws + WS_P2;
  float* P4   = ws + WS_P4;
  float* P8   = ws + WS_P8;
  float* Wdx  = ws + WS_WDX;
  float* base = ws + WS_BASE;
  float* wbuf = ws + WS_W;
  ushort* Wch = (ushort*)(ws + WS_WCH);
  ushort* Wcl = (ushort*)(ws + WS_WCL);
  ushort* Wbh = (ushort*)(ws + WS_WBH);
  ushort* Wbl = (ushort*)(ws + WS_WBL);

  // E^-1 via Neumann product: (I+A)(I+A^2)(I+A^4)(I+A^8), A = I-E, ||A||~0.2
  k_prep<<<256, 256, 0, stream>>>(E, A, S1);
  k_smallmm<<<dim3(8, 8), 256, 0, stream>>>(A,  A,  nullptr, A2, 256, 256, 0);
  k_smallmm<<<dim3(8, 8), 256, 0, stream>>>(A2, A2, nullptr, A4, 256, 256, 0);
  k_smallmm<<<dim3(8, 8), 256, 0, stream>>>(A4, A4, nullptr, A8, 256, 256, 0);
  k_smallmm<<<dim3(8, 8), 256, 0, stream>>>(S1, A2, S1,      P2, 256, 256, 1);
  k_smallmm<<<dim3(8, 8), 256, 0, stream>>>(P2, A4, P2,      P4, 256, 256, 1);
  k_smallmm<<<dim3(8, 8), 256, 0, stream>>>(P4, A8, P4,      P8, 256, 256, 1);
  k_wdx<<<dim3(8, 16), 256, 0, stream>>>(P8, F, B1, B2, Wdx);
  k_wprep<<<960, 256, 0, stream>>>(Wdx, C2, D21, D22, C1, D12, Wch, Wcl, Wbh, Wbl);

  // base = x@C1^T + u@D12^T + bv  (split-bf16 MFMA)
  k_gemm_split<384, false><<<dim3(128, 2), 256, 0, stream>>>(x, u, nullptr, Wbh, Wbl, bv, base);
  // sequential tanh solve
  k_wsolve<<<512, 256, 0, stream>>>(base, D11, Lam, wbuf);
  // [dx|y] = [x|w|u] @ Wcat^T  (split-bf16 MFMA)
  k_gemm_split<512, true><<<dim3(128, 6), 256, 0, stream>>>(x, u, wbuf, Wch, Wcl, nullptr, out);
}